// Round 12
// baseline (74.881 us; speedup 1.0000x reference)
//
#include <hip/hip_runtime.h>

#define MXN 2048   // MX == NY == 2048
#define DD  256
#define KK  100
#define KP  128    // K padded to MFMA granularity
#define NB  8

typedef __attribute__((ext_vector_type(8))) __bf16 bf16x8;
typedef __attribute__((ext_vector_type(4))) float  f32x4;

__device__ __forceinline__ unsigned short f2b(float f) {
  union { float f; unsigned u; } v; v.f = f;
  return (unsigned short)((v.u + 0x7fffu + ((v.u >> 16) & 1u)) >> 16);
}

// ---------------------------------------------------------------------------
// Kernel 0: At[k][d] = bf16(A[d][k]), zero-padded for k in [100,128). 64 KB.
// ---------------------------------------------------------------------------
__global__ __launch_bounds__(256) void k_At(const float* __restrict__ A,
                                            unsigned short* __restrict__ At) {
  int idx = blockIdx.x * 256 + threadIdx.x;   // 0 .. 128*256-1
  int k = idx >> 8, d = idx & 255;
  At[idx] = (k < KK) ? f2b(A[d * KK + k]) : (unsigned short)0;
}

// ---------------------------------------------------------------------------
// Kernel 1: XA = bf16(X @ A), sqX[r] = sum_k XA[r][k]^2.  (R4-proven body;
// measured R9 via double-launch: ~9.5 us.)
// ---------------------------------------------------------------------------
__global__ __launch_bounds__(256) void k_proj(
    const float* __restrict__ X, const float* __restrict__ Y,
    const unsigned short* __restrict__ At,
    unsigned short* __restrict__ XAo, unsigned short* __restrict__ YAo,
    float* __restrict__ sqX, float* __restrict__ sqY)
{
  __shared__ __align__(16) unsigned short Ash[128 * 256]; // [k][d] swizzled, 64 KB

  const int bid = blockIdx.x;
  const bool isY = bid >= 256;
  const int row0 = (bid & 255) * 64;
  const float* __restrict__ src = isY ? Y : X;
  unsigned short* __restrict__ dst = isY ? YAo : XAo;
  float* __restrict__ sqdst = isY ? sqY : sqX;
  const int t = threadIdx.x;

#pragma unroll
  for (int i = 0; i < 16; ++i) {
    int ch = i * 256 + t;
    int row = ch >> 5, c = ch & 31;
    bf16x8 v = *reinterpret_cast<const bf16x8*>(At + ch * 8);
    int byte = (row * 512 + c * 16) ^ ((row & 7) << 4);
    *reinterpret_cast<bf16x8*>((char*)Ash + byte) = v;
  }
  __syncthreads();

  const int w = t >> 6, l = t & 63;
  const int lr = l & 15, lk8 = (l >> 4) * 8;
  const int rowA = row0 + w * 16 + lr;

  f32x4 acc[8];
#pragma unroll
  for (int j = 0; j < 8; ++j) acc[j] = (f32x4){0.f, 0.f, 0.f, 0.f};

#pragma unroll
  for (int ks = 0; ks < 8; ++ks) {
    const int d = ks * 32 + lk8;
    const float* px = src + (size_t)rowA * DD + d;
    float4 v0 = *reinterpret_cast<const float4*>(px);
    float4 v1 = *reinterpret_cast<const float4*>(px + 4);
    bf16x8 af;
    af[0] = (__bf16)v0.x; af[1] = (__bf16)v0.y; af[2] = (__bf16)v0.z; af[3] = (__bf16)v0.w;
    af[4] = (__bf16)v1.x; af[5] = (__bf16)v1.y; af[6] = (__bf16)v1.z; af[7] = (__bf16)v1.w;
#pragma unroll
    for (int nf = 0; nf < 8; ++nf) {
      const int kq = nf * 16 + lr;
      bf16x8 bf = *reinterpret_cast<bf16x8*>(
          (char*)Ash + ((kq * 512 + d * 2) ^ ((kq & 7) << 4)));
      acc[nf] = __builtin_amdgcn_mfma_f32_16x16x32_bf16(af, bf, acc[nf], 0, 0, 0);
    }
  }

  float sq[4] = {0.f, 0.f, 0.f, 0.f};
#pragma unroll
  for (int nf = 0; nf < 8; ++nf)
#pragma unroll
    for (int reg = 0; reg < 4; ++reg) {
      union { __bf16 b; unsigned short u; } cv;
      cv.b = (__bf16)acc[nf][reg];
      float vq = (float)cv.b;
      int r = row0 + w * 16 + ((l >> 4) << 2) + reg;
      dst[(size_t)r * KP + nf * 16 + lr] = cv.u;
      sq[reg] += vq * vq;
    }
#pragma unroll
  for (int reg = 0; reg < 4; ++reg) {
    float s = sq[reg];
    s += __shfl_xor(s, 1);
    s += __shfl_xor(s, 2);
    s += __shfl_xor(s, 4);
    s += __shfl_xor(s, 8);
    if (lr == 0)
      sqdst[row0 + w * 16 + ((l >> 4) << 2) + reg] = s;
  }
}

// ---------------------------------------------------------------------------
// Kernel 2: R10 body (best measured config, 46.9 us total).
// LAUNCHED TWICE this round — double-launch ablation to measure k_cross's
// true duration (rocprof top-5 is saturated by harness fills).
// ---------------------------------------------------------------------------
__global__ __launch_bounds__(256, 4) void k_cross(
    const unsigned short* __restrict__ XA, const unsigned short* __restrict__ YA,
    const float* __restrict__ sqX, const float* __restrict__ sqY,
    float* __restrict__ out)
{
  __shared__ __align__(16) unsigned short Xsh[128 * 128];  // 32 KB swizzled

  const int bid = blockIdx.x;
  const int b   = bid & 7;             // batch -> XCD pin
  const int sh_ = bid >> 3;            // 0..127
  const int n0  = (sh_ >> 1) * 32;     // 64 strips per batch
  const int mh  = (sh_ & 1) * 8;       // m-tile half: tiles [mh, mh+8)
  const int t = threadIdx.x;
  const int w = t >> 6, l = t & 63;
  const int m_w = w * 32;              // wave's m-offset within a 128-tile
  const int lr = l & 15, lk = (l >> 4) * 8;

  bf16x8 yf[2][4];
#pragma unroll
  for (int i = 0; i < 2; ++i)
#pragma unroll
    for (int ks = 0; ks < 4; ++ks)
      yf[i][ks] = *reinterpret_cast<const bf16x8*>(
          YA + ((size_t)(b * MXN + n0 + i * 16 + lr) * KP + ks * 32 + lk));

  float syv[2][4];
#pragma unroll
  for (int i = 0; i < 2; ++i)
#pragma unroll
    for (int reg = 0; reg < 4; ++reg)
      syv[i][reg] = sqY[b * MXN + n0 + i * 16 + ((l >> 4) << 2) + reg];

  bf16x8 xr[8];
#pragma unroll
  for (int i = 0; i < 8; ++i) {
    int ch = i * 256 + t;
    int row = ch >> 4, c = ch & 15;
    xr[i] = *reinterpret_cast<const bf16x8*>(
        XA + ((size_t)(b * MXN + mh * 128 + row) * KP + c * 8));
  }

  for (int it = 0; it < 8; ++it) {
    const int mt = mh + it;

    asm volatile("s_waitcnt lgkmcnt(0)" ::: "memory");
    __builtin_amdgcn_s_barrier();
    asm volatile("" ::: "memory");

#pragma unroll
    for (int i = 0; i < 8; ++i) {
      int ch = i * 256 + t;
      int row = ch >> 4, c = ch & 15;
      int byte = (row * 256 + c * 16) ^ ((row & 7) << 4);
      *reinterpret_cast<bf16x8*>((char*)Xsh + byte) = xr[i];
    }

    asm volatile("s_waitcnt lgkmcnt(0)" ::: "memory");
    __builtin_amdgcn_s_barrier();
    asm volatile("" ::: "memory");

    if (it < 7) {
#pragma unroll
      for (int i = 0; i < 8; ++i) {
        int ch = i * 256 + t;
        int row = ch >> 4, c = ch & 15;
        xr[i] = *reinterpret_cast<const bf16x8*>(
            XA + ((size_t)(b * MXN + (mt + 1) * 128 + row) * KP + c * 8));
      }
    }

    f32x4 acc[2][2];
#pragma unroll
    for (int i = 0; i < 2; ++i)
#pragma unroll
      for (int j = 0; j < 2; ++j) acc[i][j] = (f32x4){0.f, 0.f, 0.f, 0.f};

#pragma unroll
    for (int ks = 0; ks < 4; ++ks) {
      const int d2 = ks * 64 + lk * 2;   // byte offset within row
      int rm0 = m_w + lr, rm1 = m_w + 16 + lr;
      bf16x8 b0 = *reinterpret_cast<bf16x8*>(
          (char*)Xsh + ((rm0 * 256 + d2) ^ ((rm0 & 7) << 4)));
      bf16x8 b1 = *reinterpret_cast<bf16x8*>(
          (char*)Xsh + ((rm1 * 256 + d2) ^ ((rm1 & 7) << 4)));
      acc[0][0] = __builtin_amdgcn_mfma_f32_16x16x32_bf16(yf[0][ks], b0, acc[0][0], 0, 0, 0);
      acc[0][1] = __builtin_amdgcn_mfma_f32_16x16x32_bf16(yf[0][ks], b1, acc[0][1], 0, 0, 0);
      acc[1][0] = __builtin_amdgcn_mfma_f32_16x16x32_bf16(yf[1][ks], b0, acc[1][0], 0, 0, 0);
      acc[1][1] = __builtin_amdgcn_mfma_f32_16x16x32_bf16(yf[1][ks], b1, acc[1][1], 0, 0, 0);
    }

    float sx0 = sqX[b * MXN + mt * 128 + m_w + lr];
    float sx1 = sqX[b * MXN + mt * 128 + m_w + 16 + lr];
#pragma unroll
    for (int i = 0; i < 2; ++i)
#pragma unroll
      for (int reg = 0; reg < 4; ++reg) {
        int n = n0 + i * 16 + ((l >> 4) << 2) + reg;
        size_t obase = ((size_t)b * MXN + n) * MXN + mt * 128 + m_w;
        float v0 = syv[i][reg] + sx0 - 2.0f * acc[i][0][reg];
        float v1 = syv[i][reg] + sx1 - 2.0f * acc[i][1][reg];
        out[obase + lr]      = v0 > 0.f ? v0 : 0.f;
        out[obase + 16 + lr] = v1 > 0.f ? v1 : 0.f;
      }
  }
}

extern "C" void kernel_launch(void* const* d_in, const int* in_sizes, int n_in,
                              void* d_out, int out_size, void* d_ws, size_t ws_size,
                              hipStream_t stream) {
  const float* X = (const float*)d_in[0];   // (8, 2048, 256)
  const float* Y = (const float*)d_in[1];   // (8, 2048, 256)
  const float* A = (const float*)d_in[2];   // (256, 100)
  float* out = (float*)d_out;               // (8, 2048, 2048)

  char* ws = (char*)d_ws;
  const size_t ROWS = (size_t)NB * MXN;     // 16384
  unsigned short* XAw = (unsigned short*)ws;                        // 4 MB
  unsigned short* YAw = (unsigned short*)(ws + ROWS * KP * 2);      // 4 MB
  float* sqX = (float*)(ws + 2 * ROWS * KP * 2);                    // 64 KB
  float* sqY = (float*)(ws + 2 * ROWS * KP * 2 + ROWS * 4);         // 64 KB
  unsigned short* At = (unsigned short*)(ws + 2 * ROWS * KP * 2 + 2 * ROWS * 4); // 64 KB

  k_At  <<<128, 256, 0, stream>>>(A, At);
  k_proj<<<512, 256, 0, stream>>>(X, Y, At, XAw, YAw, sqX, sqY);
  k_cross<<<1024, 256, 0, stream>>>(XAw, YAw, sqX, sqY, out);
  k_cross<<<1024, 256, 0, stream>>>(XAw, YAw, sqX, sqY, out);  // ABLATION: 2nd identical launch
}

// Round 13
// 49.107 us; speedup vs baseline: 1.5249x; 1.5249x over previous
//
#include <hip/hip_runtime.h>

#define MXN 2048   // MX == NY == 2048
#define DD  256
#define KK  100
#define KP  128    // K padded to MFMA granularity
#define NB  8

typedef __attribute__((ext_vector_type(8))) __bf16 bf16x8;
typedef __attribute__((ext_vector_type(4))) float  f32x4;

__device__ __forceinline__ unsigned short f2b(float f) {
  union { float f; unsigned u; } v; v.f = f;
  return (unsigned short)((v.u + 0x7fffu + ((v.u >> 16) & 1u)) >> 16);
}

// ---------------------------------------------------------------------------
// Kernel 0: At[k][d] = bf16(A[d][k]), zero-padded for k in [100,128). 64 KB.
// ---------------------------------------------------------------------------
__global__ __launch_bounds__(256) void k_At(const float* __restrict__ A,
                                            unsigned short* __restrict__ At) {
  int idx = blockIdx.x * 256 + threadIdx.x;   // 0 .. 128*256-1
  int k = idx >> 8, d = idx & 255;
  At[idx] = (k < KK) ? f2b(A[d * KK + k]) : (unsigned short)0;
}

// ---------------------------------------------------------------------------
// Kernel 1: XA = bf16(X @ A), sqX[r] = sum_k XA[r][k]^2.  (R4-proven body;
// measured ~9.7 us via R9 double-launch.)
// ---------------------------------------------------------------------------
__global__ __launch_bounds__(256) void k_proj(
    const float* __restrict__ X, const float* __restrict__ Y,
    const unsigned short* __restrict__ At,
    unsigned short* __restrict__ XAo, unsigned short* __restrict__ YAo,
    float* __restrict__ sqX, float* __restrict__ sqY)
{
  __shared__ __align__(16) unsigned short Ash[128 * 256]; // [k][d] swizzled, 64 KB

  const int bid = blockIdx.x;
  const bool isY = bid >= 256;
  const int row0 = (bid & 255) * 64;
  const float* __restrict__ src = isY ? Y : X;
  unsigned short* __restrict__ dst = isY ? YAo : XAo;
  float* __restrict__ sqdst = isY ? sqY : sqX;
  const int t = threadIdx.x;

#pragma unroll
  for (int i = 0; i < 16; ++i) {
    int ch = i * 256 + t;
    int row = ch >> 5, c = ch & 31;
    bf16x8 v = *reinterpret_cast<const bf16x8*>(At + ch * 8);
    int byte = (row * 512 + c * 16) ^ ((row & 7) << 4);
    *reinterpret_cast<bf16x8*>((char*)Ash + byte) = v;
  }
  __syncthreads();

  const int w = t >> 6, l = t & 63;
  const int lr = l & 15, lk8 = (l >> 4) * 8;
  const int rowA = row0 + w * 16 + lr;

  f32x4 acc[8];
#pragma unroll
  for (int j = 0; j < 8; ++j) acc[j] = (f32x4){0.f, 0.f, 0.f, 0.f};

#pragma unroll
  for (int ks = 0; ks < 8; ++ks) {
    const int d = ks * 32 + lk8;
    const float* px = src + (size_t)rowA * DD + d;
    float4 v0 = *reinterpret_cast<const float4*>(px);
    float4 v1 = *reinterpret_cast<const float4*>(px + 4);
    bf16x8 af;
    af[0] = (__bf16)v0.x; af[1] = (__bf16)v0.y; af[2] = (__bf16)v0.z; af[3] = (__bf16)v0.w;
    af[4] = (__bf16)v1.x; af[5] = (__bf16)v1.y; af[6] = (__bf16)v1.z; af[7] = (__bf16)v1.w;
#pragma unroll
    for (int nf = 0; nf < 8; ++nf) {
      const int kq = nf * 16 + lr;
      bf16x8 bf = *reinterpret_cast<bf16x8*>(
          (char*)Ash + ((kq * 512 + d * 2) ^ ((kq & 7) << 4)));
      acc[nf] = __builtin_amdgcn_mfma_f32_16x16x32_bf16(af, bf, acc[nf], 0, 0, 0);
    }
  }

  float sq[4] = {0.f, 0.f, 0.f, 0.f};
#pragma unroll
  for (int nf = 0; nf < 8; ++nf)
#pragma unroll
    for (int reg = 0; reg < 4; ++reg) {
      union { __bf16 b; unsigned short u; } cv;
      cv.b = (__bf16)acc[nf][reg];
      float vq = (float)cv.b;
      int r = row0 + w * 16 + ((l >> 4) << 2) + reg;
      dst[(size_t)r * KP + nf * 16 + lr] = cv.u;
      sq[reg] += vq * vq;
    }
#pragma unroll
  for (int reg = 0; reg < 4; ++reg) {
    float s = sq[reg];
    s += __shfl_xor(s, 1);
    s += __shfl_xor(s, 2);
    s += __shfl_xor(s, 4);
    s += __shfl_xor(s, 8);
    if (lr == 0)
      sqdst[row0 + w * 16 + ((l >> 4) << 2) + reg] = s;
  }
}

// ---------------------------------------------------------------------------
// Kernel 2 (v10): WAVE-PRIVATE staging, ZERO barriers. Insight from R12's
// ablation (T_cross = 28 us vs ~21 floor): the 4 waves of a block share NO
// LDS data (each reads only its own 32-row m-slice), so block-wide staging
// + 16 barrier pairs was pure lock-step. Each wave now stages its slice
// into its own 8 KB LDS quarter; within-wave DS ops are in-order by HW, so
// no barriers or fences at all. Reg-prefetch of tile t+1 kept (the LDS
// round-trip decouples L2 latency from MFMA — R6's lesson). 16 waves/CU
// drift freely -> store/load/LDS phases decorrelate across the CU.
// ---------------------------------------------------------------------------
__global__ __launch_bounds__(256, 4) void k_cross(
    const unsigned short* __restrict__ XA, const unsigned short* __restrict__ YA,
    const float* __restrict__ sqX, const float* __restrict__ sqY,
    float* __restrict__ out)
{
  __shared__ __align__(16) unsigned short Xsh[4][64 * 64];  // 8 KB per wave

  const int bid = blockIdx.x;
  const int b   = bid & 7;             // batch -> XCD pin
  const int sh_ = bid >> 3;            // 0..127
  const int n0  = (sh_ >> 1) * 32;     // 64 strips per batch
  const int mh  = (sh_ & 1) * 8;       // m-tile half: tiles [mh, mh+8)
  const int t = threadIdx.x;
  const int w = t >> 6, l = t & 63;
  const int m_w = w * 32;              // wave's m-offset within a 128-tile
  const int lr = l & 15, lk = (l >> 4) * 8;
  char* const wsh = (char*)Xsh[w];     // this wave's private 8 KB

  // Y fragments, once: rows n0+i*16+lr, cols ks*32+lk..+8.  (32 VGPR)
  bf16x8 yf[2][4];
#pragma unroll
  for (int i = 0; i < 2; ++i)
#pragma unroll
    for (int ks = 0; ks < 4; ++ks)
      yf[i][ks] = *reinterpret_cast<const bf16x8*>(
          YA + ((size_t)(b * MXN + n0 + i * 16 + lr) * KP + ks * 32 + lk));

  // This lane's 8 sqY values.
  float syv[2][4];
#pragma unroll
  for (int i = 0; i < 2; ++i)
#pragma unroll
    for (int reg = 0; reg < 4; ++reg)
      syv[i][reg] = sqY[b * MXN + n0 + i * 16 + ((l >> 4) << 2) + reg];

  // Wave-private prefetch of the wave's 32-row slice of the first tile:
  // 8 chunks of 16B per lane; chunk ch = i*64+l -> row = ch>>4 (0..31),
  // c = ch&15. 16 lanes x 16B = 256B contiguous per row.
  bf16x8 xr[8];
#pragma unroll
  for (int i = 0; i < 8; ++i) {
    int ch = i * 64 + l;
    int row = ch >> 4, c = ch & 15;
    xr[i] = *reinterpret_cast<const bf16x8*>(
        XA + ((size_t)(b * MXN + mh * 128 + m_w + row) * KP + c * 8));
  }

  for (int it = 0; it < 8; ++it) {
    const int mt = mh + it;

    // Write this wave's slice into its private LDS region (swizzled).
    // In-order DS pipe: the reads below see these writes, no fence needed.
#pragma unroll
    for (int i = 0; i < 8; ++i) {
      int ch = i * 64 + l;
      int row = ch >> 4, c = ch & 15;
      int byte = (row * 256 + c * 16) ^ ((row & 7) << 4);
      *reinterpret_cast<bf16x8*>(wsh + byte) = xr[i];
    }

    // Issue next tile's loads now; consumed by NEXT iteration's ds_write.
    if (it < 7) {
#pragma unroll
      for (int i = 0; i < 8; ++i) {
        int ch = i * 64 + l;
        int row = ch >> 4, c = ch & 15;
        xr[i] = *reinterpret_cast<const bf16x8*>(
            XA + ((size_t)(b * MXN + (mt + 1) * 128 + m_w + row) * KP + c * 8));
      }
    }

    // Compute 32n x 32m: rows of the slice are 0..31 (slice-local).
    f32x4 acc[2][2];
#pragma unroll
    for (int i = 0; i < 2; ++i)
#pragma unroll
      for (int j = 0; j < 2; ++j) acc[i][j] = (f32x4){0.f, 0.f, 0.f, 0.f};

#pragma unroll
    for (int ks = 0; ks < 4; ++ks) {
      const int d2 = ks * 64 + lk * 2;   // byte offset within row
      int rm0 = lr, rm1 = 16 + lr;       // slice-local rows
      bf16x8 b0 = *reinterpret_cast<bf16x8*>(
          wsh + ((rm0 * 256 + d2) ^ ((rm0 & 7) << 4)));
      bf16x8 b1 = *reinterpret_cast<bf16x8*>(
          wsh + ((rm1 * 256 + d2) ^ ((rm1 & 7) << 4)));
      acc[0][0] = __builtin_amdgcn_mfma_f32_16x16x32_bf16(yf[0][ks], b0, acc[0][0], 0, 0, 0);
      acc[0][1] = __builtin_amdgcn_mfma_f32_16x16x32_bf16(yf[0][ks], b1, acc[0][1], 0, 0, 0);
      acc[1][0] = __builtin_amdgcn_mfma_f32_16x16x32_bf16(yf[1][ks], b0, acc[1][0], 0, 0, 0);
      acc[1][1] = __builtin_amdgcn_mfma_f32_16x16x32_bf16(yf[1][ks], b1, acc[1][1], 0, 0, 0);
    }

    // Epilogue (R10-proven scalar-store pattern).
    float sx0 = sqX[b * MXN + mt * 128 + m_w + lr];
    float sx1 = sqX[b * MXN + mt * 128 + m_w + 16 + lr];
#pragma unroll
    for (int i = 0; i < 2; ++i)
#pragma unroll
      for (int reg = 0; reg < 4; ++reg) {
        int n = n0 + i * 16 + ((l >> 4) << 2) + reg;
        size_t obase = ((size_t)b * MXN + n) * MXN + mt * 128 + m_w;
        float v0 = syv[i][reg] + sx0 - 2.0f * acc[i][0][reg];
        float v1 = syv[i][reg] + sx1 - 2.0f * acc[i][1][reg];
        out[obase + lr]      = v0 > 0.f ? v0 : 0.f;
        out[obase + 16 + lr] = v1 > 0.f ? v1 : 0.f;
      }
  }
}

extern "C" void kernel_launch(void* const* d_in, const int* in_sizes, int n_in,
                              void* d_out, int out_size, void* d_ws, size_t ws_size,
                              hipStream_t stream) {
  const float* X = (const float*)d_in[0];   // (8, 2048, 256)
  const float* Y = (const float*)d_in[1];   // (8, 2048, 256)
  const float* A = (const float*)d_in[2];   // (256, 100)
  float* out = (float*)d_out;               // (8, 2048, 2048)

  char* ws = (char*)d_ws;
  const size_t ROWS = (size_t)NB * MXN;     // 16384
  unsigned short* XAw = (unsigned short*)ws;                        // 4 MB
  unsigned short* YAw = (unsigned short*)(ws + ROWS * KP * 2);      // 4 MB
  float* sqX = (float*)(ws + 2 * ROWS * KP * 2);                    // 64 KB
  float* sqY = (float*)(ws + 2 * ROWS * KP * 2 + ROWS * 4);         // 64 KB
  unsigned short* At = (unsigned short*)(ws + 2 * ROWS * KP * 2 + 2 * ROWS * 4); // 64 KB

  k_At  <<<128, 256, 0, stream>>>(A, At);
  k_proj<<<512, 256, 0, stream>>>(X, Y, At, XAw, YAw, sqX, sqY);
  k_cross<<<1024, 256, 0, stream>>>(XAw, YAw, sqX, sqY, out);
}

// Round 14
// 48.015 us; speedup vs baseline: 1.5595x; 1.0227x over previous
//
#include <hip/hip_runtime.h>

#define MXN 2048   // MX == NY == 2048
#define DD  256
#define KK  100
#define KP  128    // K padded to MFMA granularity
#define NB  8

typedef __attribute__((ext_vector_type(8))) __bf16 bf16x8;
typedef __attribute__((ext_vector_type(4))) float  f32x4;

// ---------------------------------------------------------------------------
// Kernel 1: XA = bf16(X @ A), sqX[r] = sum_k XA[r][k]^2.
// At build is now INLINE (per-block, redundant): 25 coalesced float4 loads of
// A (102 KB, L2-resident) + magic-div transpose into swizzled Ash[k][d],
// zero-padded k in [100,128). Kills the k_At kernel + one launch gap
// (measured At+gaps = 9.2 us in R12's budget).
// MFMA body unchanged (R4-proven, ~9.7 us measured via R9 double-launch).
// ---------------------------------------------------------------------------
__global__ __launch_bounds__(256) void k_proj(
    const float* __restrict__ X, const float* __restrict__ Y,
    const float* __restrict__ A,
    unsigned short* __restrict__ XAo, unsigned short* __restrict__ YAo,
    float* __restrict__ sqX, float* __restrict__ sqY)
{
  __shared__ __align__(16) unsigned short Ash[128 * 256]; // [k][d] swizzled, 64 KB

  const int bid = blockIdx.x;
  const bool isY = bid >= 256;
  const int row0 = (bid & 255) * 64;
  const float* __restrict__ src = isY ? Y : X;
  unsigned short* __restrict__ dst = isY ? YAo : XAo;
  float* __restrict__ sqdst = isY ? sqY : sqX;
  const int t = threadIdx.x;

  // --- Inline At build ---
  // Zero-fill pad rows k in [100,128): bytes [51200, 65536), 56 B/thread.
  {
    char* p = (char*)Ash + 51200 + t * 56;
#pragma unroll
    for (int i = 0; i < 7; ++i)
      *reinterpret_cast<unsigned long long*>(p + i * 8) = 0ull;
  }
  // Transpose A (f32 [d][100]) -> Ash (bf16 [k][d], swizzled), coalesced reads.
#pragma unroll
  for (int i = 0; i < 25; ++i) {
    int f = i * 256 + t;              // float4 index, 6400 total
    float4 v = reinterpret_cast<const float4*>(A)[f];
#pragma unroll
    for (int j = 0; j < 4; ++j) {
      unsigned e = f * 4 + j;         // element index in A
      unsigned d = e / 100u;          // magic-mul division
      unsigned k = e - d * 100u;
      union { __bf16 b; unsigned short u; } cv;
      cv.b = (__bf16)((j == 0) ? v.x : (j == 1) ? v.y : (j == 2) ? v.z : v.w);
      int byte = (k * 512 + d * 2) ^ ((k & 7) << 4);
      *reinterpret_cast<unsigned short*>((char*)Ash + byte) = cv.u;
    }
  }
  __syncthreads();

  const int w = t >> 6, l = t & 63;
  const int lr = l & 15, lk8 = (l >> 4) * 8;
  const int rowA = row0 + w * 16 + lr;

  f32x4 acc[8];
#pragma unroll
  for (int j = 0; j < 8; ++j) acc[j] = (f32x4){0.f, 0.f, 0.f, 0.f};

#pragma unroll
  for (int ks = 0; ks < 8; ++ks) {
    const int d = ks * 32 + lk8;
    const float* px = src + (size_t)rowA * DD + d;
    float4 v0 = *reinterpret_cast<const float4*>(px);
    float4 v1 = *reinterpret_cast<const float4*>(px + 4);
    bf16x8 af;
    af[0] = (__bf16)v0.x; af[1] = (__bf16)v0.y; af[2] = (__bf16)v0.z; af[3] = (__bf16)v0.w;
    af[4] = (__bf16)v1.x; af[5] = (__bf16)v1.y; af[6] = (__bf16)v1.z; af[7] = (__bf16)v1.w;
#pragma unroll
    for (int nf = 0; nf < 8; ++nf) {
      const int kq = nf * 16 + lr;
      bf16x8 bf = *reinterpret_cast<bf16x8*>(
          (char*)Ash + ((kq * 512 + d * 2) ^ ((kq & 7) << 4)));
      acc[nf] = __builtin_amdgcn_mfma_f32_16x16x32_bf16(af, bf, acc[nf], 0, 0, 0);
    }
  }

  float sq[4] = {0.f, 0.f, 0.f, 0.f};
#pragma unroll
  for (int nf = 0; nf < 8; ++nf)
#pragma unroll
    for (int reg = 0; reg < 4; ++reg) {
      union { __bf16 b; unsigned short u; } cv;
      cv.b = (__bf16)acc[nf][reg];
      float vq = (float)cv.b;
      int r = row0 + w * 16 + ((l >> 4) << 2) + reg;
      dst[(size_t)r * KP + nf * 16 + lr] = cv.u;
      sq[reg] += vq * vq;
    }
#pragma unroll
  for (int reg = 0; reg < 4; ++reg) {
    float s = sq[reg];
    s += __shfl_xor(s, 1);
    s += __shfl_xor(s, 2);
    s += __shfl_xor(s, 4);
    s += __shfl_xor(s, 8);
    if (lr == 0)
      sqdst[row0 + w * 16 + ((l >> 4) << 2) + reg] = s;
  }
}

// ---------------------------------------------------------------------------
// Kernel 2: R10 body exactly (best measured: T_cross = 28.0 us, at the
// mixed read+write HBM-stream floor; six structural variants all >= this).
// ---------------------------------------------------------------------------
__global__ __launch_bounds__(256, 4) void k_cross(
    const unsigned short* __restrict__ XA, const unsigned short* __restrict__ YA,
    const float* __restrict__ sqX, const float* __restrict__ sqY,
    float* __restrict__ out)
{
  __shared__ __align__(16) unsigned short Xsh[128 * 128];  // 32 KB swizzled

  const int bid = blockIdx.x;
  const int b   = bid & 7;             // batch -> XCD pin
  const int sh_ = bid >> 3;            // 0..127
  const int n0  = (sh_ >> 1) * 32;     // 64 strips per batch
  const int mh  = (sh_ & 1) * 8;       // m-tile half: tiles [mh, mh+8)
  const int t = threadIdx.x;
  const int w = t >> 6, l = t & 63;
  const int m_w = w * 32;              // wave's m-offset within a 128-tile
  const int lr = l & 15, lk = (l >> 4) * 8;

  bf16x8 yf[2][4];
#pragma unroll
  for (int i = 0; i < 2; ++i)
#pragma unroll
    for (int ks = 0; ks < 4; ++ks)
      yf[i][ks] = *reinterpret_cast<const bf16x8*>(
          YA + ((size_t)(b * MXN + n0 + i * 16 + lr) * KP + ks * 32 + lk));

  float syv[2][4];
#pragma unroll
  for (int i = 0; i < 2; ++i)
#pragma unroll
    for (int reg = 0; reg < 4; ++reg)
      syv[i][reg] = sqY[b * MXN + n0 + i * 16 + ((l >> 4) << 2) + reg];

  bf16x8 xr[8];
#pragma unroll
  for (int i = 0; i < 8; ++i) {
    int ch = i * 256 + t;
    int row = ch >> 4, c = ch & 15;
    xr[i] = *reinterpret_cast<const bf16x8*>(
        XA + ((size_t)(b * MXN + mh * 128 + row) * KP + c * 8));
  }

  for (int it = 0; it < 8; ++it) {
    const int mt = mh + it;

    asm volatile("s_waitcnt lgkmcnt(0)" ::: "memory");
    __builtin_amdgcn_s_barrier();
    asm volatile("" ::: "memory");

#pragma unroll
    for (int i = 0; i < 8; ++i) {
      int ch = i * 256 + t;
      int row = ch >> 4, c = ch & 15;
      int byte = (row * 256 + c * 16) ^ ((row & 7) << 4);
      *reinterpret_cast<bf16x8*>((char*)Xsh + byte) = xr[i];
    }

    asm volatile("s_waitcnt lgkmcnt(0)" ::: "memory");
    __builtin_amdgcn_s_barrier();
    asm volatile("" ::: "memory");

    if (it < 7) {
#pragma unroll
      for (int i = 0; i < 8; ++i) {
        int ch = i * 256 + t;
        int row = ch >> 4, c = ch & 15;
        xr[i] = *reinterpret_cast<const bf16x8*>(
            XA + ((size_t)(b * MXN + (mt + 1) * 128 + row) * KP + c * 8));
      }
    }

    f32x4 acc[2][2];
#pragma unroll
    for (int i = 0; i < 2; ++i)
#pragma unroll
      for (int j = 0; j < 2; ++j) acc[i][j] = (f32x4){0.f, 0.f, 0.f, 0.f};

#pragma unroll
    for (int ks = 0; ks < 4; ++ks) {
      const int d2 = ks * 64 + lk * 2;   // byte offset within row
      int rm0 = m_w + lr, rm1 = m_w + 16 + lr;
      bf16x8 b0 = *reinterpret_cast<bf16x8*>(
          (char*)Xsh + ((rm0 * 256 + d2) ^ ((rm0 & 7) << 4)));
      bf16x8 b1 = *reinterpret_cast<bf16x8*>(
          (char*)Xsh + ((rm1 * 256 + d2) ^ ((rm1 & 7) << 4)));
      acc[0][0] = __builtin_amdgcn_mfma_f32_16x16x32_bf16(yf[0][ks], b0, acc[0][0], 0, 0, 0);
      acc[0][1] = __builtin_amdgcn_mfma_f32_16x16x32_bf16(yf[0][ks], b1, acc[0][1], 0, 0, 0);
      acc[1][0] = __builtin_amdgcn_mfma_f32_16x16x32_bf16(yf[1][ks], b0, acc[1][0], 0, 0, 0);
      acc[1][1] = __builtin_amdgcn_mfma_f32_16x16x32_bf16(yf[1][ks], b1, acc[1][1], 0, 0, 0);
    }

    float sx0 = sqX[b * MXN + mt * 128 + m_w + lr];
    float sx1 = sqX[b * MXN + mt * 128 + m_w + 16 + lr];
#pragma unroll
    for (int i = 0; i < 2; ++i)
#pragma unroll
      for (int reg = 0; reg < 4; ++reg) {
        int n = n0 + i * 16 + ((l >> 4) << 2) + reg;
        size_t obase = ((size_t)b * MXN + n) * MXN + mt * 128 + m_w;
        float v0 = syv[i][reg] + sx0 - 2.0f * acc[i][0][reg];
        float v1 = syv[i][reg] + sx1 - 2.0f * acc[i][1][reg];
        out[obase + lr]      = v0 > 0.f ? v0 : 0.f;
        out[obase + 16 + lr] = v1 > 0.f ? v1 : 0.f;
      }
  }
}

extern "C" void kernel_launch(void* const* d_in, const int* in_sizes, int n_in,
                              void* d_out, int out_size, void* d_ws, size_t ws_size,
                              hipStream_t stream) {
  const float* X = (const float*)d_in[0];   // (8, 2048, 256)
  const float* Y = (const float*)d_in[1];   // (8, 2048, 256)
  const float* A = (const float*)d_in[2];   // (256, 100)
  float* out = (float*)d_out;               // (8, 2048, 2048)

  char* ws = (char*)d_ws;
  const size_t ROWS = (size_t)NB * MXN;     // 16384
  unsigned short* XAw = (unsigned short*)ws;                        // 4 MB
  unsigned short* YAw = (unsigned short*)(ws + ROWS * KP * 2);      // 4 MB
  float* sqX = (float*)(ws + 2 * ROWS * KP * 2);                    // 64 KB
  float* sqY = (float*)(ws + 2 * ROWS * KP * 2 + ROWS * 4);         // 64 KB

  k_proj<<<512, 256, 0, stream>>>(X, Y, A, XAw, YAw, sqX, sqY);
  k_cross<<<1024, 256, 0, stream>>>(XAw, YAw, sqX, sqY, out);
}

// Round 15
// 46.265 us; speedup vs baseline: 1.6185x; 1.0378x over previous
//
#include <hip/hip_runtime.h>

#define MXN 2048   // MX == NY == 2048
#define DD  256
#define KK  100
#define KP  128    // K padded to MFMA granularity
#define NB  8

typedef __attribute__((ext_vector_type(8))) __bf16 bf16x8;
typedef __attribute__((ext_vector_type(4))) float  f32x4;

// ---------------------------------------------------------------------------
// Kernel 1: XA = bf16(X @ A), sqX[r] = sum_k XA[r][k]^2.
// Inline At build v2, bank-conflict-free: thread t owns d = t. Reads A's
// CONTIGUOUS row d (25 x float4, L1-resident), writes column d into swizzled
// Ash[k][d]. Per ds_write_b16, consecutive lanes have byte stride 2 -> 2
// lanes/bank = free (R14's version had stride 2048 -> same-bank 25-way
// conflict, +7 us). Zero-pad rows [100,128) = physical bytes [51200,65536)
// (swizzle XOR only touches bits 4..6, stays within each 512-B row).
// MFMA body unchanged (R4-proven).
// ---------------------------------------------------------------------------
__global__ __launch_bounds__(256) void k_proj(
    const float* __restrict__ X, const float* __restrict__ Y,
    const float* __restrict__ A,
    unsigned short* __restrict__ XAo, unsigned short* __restrict__ YAo,
    float* __restrict__ sqX, float* __restrict__ sqY)
{
  __shared__ __align__(16) unsigned short Ash[128 * 256]; // [k][d] swizzled, 64 KB

  const int bid = blockIdx.x;
  const bool isY = bid >= 256;
  const int row0 = (bid & 255) * 64;
  const float* __restrict__ src = isY ? Y : X;
  unsigned short* __restrict__ dst = isY ? YAo : XAo;
  float* __restrict__ sqdst = isY ? sqY : sqX;
  const int t = threadIdx.x;

  // --- Inline At build (bank-safe) ---
  // Zero-fill pad rows k in [100,128): bytes [51200, 65536), 56 B/thread.
  {
    char* p = (char*)Ash + 51200 + t * 56;
#pragma unroll
    for (int i = 0; i < 7; ++i)
      *reinterpret_cast<unsigned long long*>(p + i * 8) = 0ull;
  }
  // Thread t = column d: read A[t][0..99] contiguous, scatter down column t.
  {
    const float4* arow = reinterpret_cast<const float4*>(A + t * KK); // 400 B
#pragma unroll
    for (int j = 0; j < 25; ++j) {
      float4 v = arow[j];
#pragma unroll
      for (int q = 0; q < 4; ++q) {
        int k = j * 4 + q;
        union { __bf16 b; unsigned short u; } cv;
        cv.b = (__bf16)((q == 0) ? v.x : (q == 1) ? v.y : (q == 2) ? v.z : v.w);
        int byte = (k * 512 + t * 2) ^ ((k & 7) << 4);
        *reinterpret_cast<unsigned short*>((char*)Ash + byte) = cv.u;
      }
    }
  }
  __syncthreads();

  const int w = t >> 6, l = t & 63;
  const int lr = l & 15, lk8 = (l >> 4) * 8;
  const int rowA = row0 + w * 16 + lr;

  f32x4 acc[8];
#pragma unroll
  for (int j = 0; j < 8; ++j) acc[j] = (f32x4){0.f, 0.f, 0.f, 0.f};

#pragma unroll
  for (int ks = 0; ks < 8; ++ks) {
    const int d = ks * 32 + lk8;
    const float* px = src + (size_t)rowA * DD + d;
    float4 v0 = *reinterpret_cast<const float4*>(px);
    float4 v1 = *reinterpret_cast<const float4*>(px + 4);
    bf16x8 af;
    af[0] = (__bf16)v0.x; af[1] = (__bf16)v0.y; af[2] = (__bf16)v0.z; af[3] = (__bf16)v0.w;
    af[4] = (__bf16)v1.x; af[5] = (__bf16)v1.y; af[6] = (__bf16)v1.z; af[7] = (__bf16)v1.w;
#pragma unroll
    for (int nf = 0; nf < 8; ++nf) {
      const int kq = nf * 16 + lr;
      bf16x8 bf = *reinterpret_cast<bf16x8*>(
          (char*)Ash + ((kq * 512 + d * 2) ^ ((kq & 7) << 4)));
      acc[nf] = __builtin_amdgcn_mfma_f32_16x16x32_bf16(af, bf, acc[nf], 0, 0, 0);
    }
  }

  float sq[4] = {0.f, 0.f, 0.f, 0.f};
#pragma unroll
  for (int nf = 0; nf < 8; ++nf)
#pragma unroll
    for (int reg = 0; reg < 4; ++reg) {
      union { __bf16 b; unsigned short u; } cv;
      cv.b = (__bf16)acc[nf][reg];
      float vq = (float)cv.b;
      int r = row0 + w * 16 + ((l >> 4) << 2) + reg;
      dst[(size_t)r * KP + nf * 16 + lr] = cv.u;
      sq[reg] += vq * vq;
    }
#pragma unroll
  for (int reg = 0; reg < 4; ++reg) {
    float s = sq[reg];
    s += __shfl_xor(s, 1);
    s += __shfl_xor(s, 2);
    s += __shfl_xor(s, 4);
    s += __shfl_xor(s, 8);
    if (lr == 0)
      sqdst[row0 + w * 16 + ((l >> 4) << 2) + reg] = s;
  }
}

// ---------------------------------------------------------------------------
// Kernel 2: R10 body exactly (best measured: T_cross = 28.0 us, at the
// mixed read+write HBM-stream floor; six structural variants all >= this).
// ---------------------------------------------------------------------------
__global__ __launch_bounds__(256, 4) void k_cross(
    const unsigned short* __restrict__ XA, const unsigned short* __restrict__ YA,
    const float* __restrict__ sqX, const float* __restrict__ sqY,
    float* __restrict__ out)
{
  __shared__ __align__(16) unsigned short Xsh[128 * 128];  // 32 KB swizzled

  const int bid = blockIdx.x;
  const int b   = bid & 7;             // batch -> XCD pin
  const int sh_ = bid >> 3;            // 0..127
  const int n0  = (sh_ >> 1) * 32;     // 64 strips per batch
  const int mh  = (sh_ & 1) * 8;       // m-tile half: tiles [mh, mh+8)
  const int t = threadIdx.x;
  const int w = t >> 6, l = t & 63;
  const int m_w = w * 32;              // wave's m-offset within a 128-tile
  const int lr = l & 15, lk = (l >> 4) * 8;

  bf16x8 yf[2][4];
#pragma unroll
  for (int i = 0; i < 2; ++i)
#pragma unroll
    for (int ks = 0; ks < 4; ++ks)
      yf[i][ks] = *reinterpret_cast<const bf16x8*>(
          YA + ((size_t)(b * MXN + n0 + i * 16 + lr) * KP + ks * 32 + lk));

  float syv[2][4];
#pragma unroll
  for (int i = 0; i < 2; ++i)
#pragma unroll
    for (int reg = 0; reg < 4; ++reg)
      syv[i][reg] = sqY[b * MXN + n0 + i * 16 + ((l >> 4) << 2) + reg];

  bf16x8 xr[8];
#pragma unroll
  for (int i = 0; i < 8; ++i) {
    int ch = i * 256 + t;
    int row = ch >> 4, c = ch & 15;
    xr[i] = *reinterpret_cast<const bf16x8*>(
        XA + ((size_t)(b * MXN + mh * 128 + row) * KP + c * 8));
  }

  for (int it = 0; it < 8; ++it) {
    const int mt = mh + it;

    asm volatile("s_waitcnt lgkmcnt(0)" ::: "memory");
    __builtin_amdgcn_s_barrier();
    asm volatile("" ::: "memory");

#pragma unroll
    for (int i = 0; i < 8; ++i) {
      int ch = i * 256 + t;
      int row = ch >> 4, c = ch & 15;
      int byte = (row * 256 + c * 16) ^ ((row & 7) << 4);
      *reinterpret_cast<bf16x8*>((char*)Xsh + byte) = xr[i];
    }

    asm volatile("s_waitcnt lgkmcnt(0)" ::: "memory");
    __builtin_amdgcn_s_barrier();
    asm volatile("" ::: "memory");

    if (it < 7) {
#pragma unroll
      for (int i = 0; i < 8; ++i) {
        int ch = i * 256 + t;
        int row = ch >> 4, c = ch & 15;
        xr[i] = *reinterpret_cast<const bf16x8*>(
            XA + ((size_t)(b * MXN + (mt + 1) * 128 + row) * KP + c * 8));
      }
    }

    f32x4 acc[2][2];
#pragma unroll
    for (int i = 0; i < 2; ++i)
#pragma unroll
      for (int j = 0; j < 2; ++j) acc[i][j] = (f32x4){0.f, 0.f, 0.f, 0.f};

#pragma unroll
    for (int ks = 0; ks < 4; ++ks) {
      const int d2 = ks * 64 + lk * 2;   // byte offset within row
      int rm0 = m_w + lr, rm1 = m_w + 16 + lr;
      bf16x8 b0 = *reinterpret_cast<bf16x8*>(
          (char*)Xsh + ((rm0 * 256 + d2) ^ ((rm0 & 7) << 4)));
      bf16x8 b1 = *reinterpret_cast<bf16x8*>(
          (char*)Xsh + ((rm1 * 256 + d2) ^ ((rm1 & 7) << 4)));
      acc[0][0] = __builtin_amdgcn_mfma_f32_16x16x32_bf16(yf[0][ks], b0, acc[0][0], 0, 0, 0);
      acc[0][1] = __builtin_amdgcn_mfma_f32_16x16x32_bf16(yf[0][ks], b1, acc[0][1], 0, 0, 0);
      acc[1][0] = __builtin_amdgcn_mfma_f32_16x16x32_bf16(yf[1][ks], b0, acc[1][0], 0, 0, 0);
      acc[1][1] = __builtin_amdgcn_mfma_f32_16x16x32_bf16(yf[1][ks], b1, acc[1][1], 0, 0, 0);
    }

    float sx0 = sqX[b * MXN + mt * 128 + m_w + lr];
    float sx1 = sqX[b * MXN + mt * 128 + m_w + 16 + lr];
#pragma unroll
    for (int i = 0; i < 2; ++i)
#pragma unroll
      for (int reg = 0; reg < 4; ++reg) {
        int n = n0 + i * 16 + ((l >> 4) << 2) + reg;
        size_t obase = ((size_t)b * MXN + n) * MXN + mt * 128 + m_w;
        float v0 = syv[i][reg] + sx0 - 2.0f * acc[i][0][reg];
        float v1 = syv[i][reg] + sx1 - 2.0f * acc[i][1][reg];
        out[obase + lr]      = v0 > 0.f ? v0 : 0.f;
        out[obase + 16 + lr] = v1 > 0.f ? v1 : 0.f;
      }
  }
}

extern "C" void kernel_launch(void* const* d_in, const int* in_sizes, int n_in,
                              void* d_out, int out_size, void* d_ws, size_t ws_size,
                              hipStream_t stream) {
  const float* X = (const float*)d_in[0];   // (8, 2048, 256)
  const float* Y = (const float*)d_in[1];   // (8, 2048, 256)
  const float* A = (const float*)d_in[2];   // (256, 100)
  float* out = (float*)d_out;               // (8, 2048, 2048)

  char* ws = (char*)d_ws;
  const size_t ROWS = (size_t)NB * MXN;     // 16384
  unsigned short* XAw = (unsigned short*)ws;                        // 4 MB
  unsigned short* YAw = (unsigned short*)(ws + ROWS * KP * 2);      // 4 MB
  float* sqX = (float*)(ws + 2 * ROWS * KP * 2);                    // 64 KB
  float* sqY = (float*)(ws + 2 * ROWS * KP * 2 + ROWS * 4);         // 64 KB

  k_proj<<<512, 256, 0, stream>>>(X, Y, A, XAw, YAw, sqX, sqY);
  k_cross<<<1024, 256, 0, stream>>>(XAw, YAw, sqX, sqY, out);
}